// Round 3
// baseline (106.094 us; speedup 1.0000x reference)
//
#include <hip/hip_runtime.h>

// Problem constants (match reference): B=1024, L=256, H=128
#define L_ 256
#define H_ 128

// base-2 softmax scale: (1/sqrt(384)) * log2(e)
// Scores are tiny (embeddings ~N(0,0.02^2) => |kk| < ~0.1): exp2 without
// max-subtraction is safe; softmax is shift-invariant. (Verified: absmax
// unchanged at 6.1e-5 in round 2.)
#define KSCALE 0.07362222315f

// ---- DPP cross-lane adds (VALU-latency) ----
template <int CTRL>
__device__ __forceinline__ float dpp_add(float v) {
    return v + __int_as_float(__builtin_amdgcn_update_dpp(
        0, __float_as_int(v), CTRL, 0xF, 0xF, true));
}

// Sum across each 16-lane row; result valid in ALL 16 lanes.
__device__ __forceinline__ float dppReduce16(float v) {
    v = dpp_add<0xB1>(v);   // quad_perm [1,0,3,2]
    v = dpp_add<0x4E>(v);   // quad_perm [2,3,0,1]
    v = dpp_add<0x141>(v);  // row_half_mirror
    v = dpp_add<0x140>(v);  // row_mirror
    return v;
}

// Sum across each 32-lane half-wave; result valid in all 32 lanes.
// 4 DPP stages + one ds_swizzle (xor 16 within 32-lane group).
__device__ __forceinline__ float reduce32(float v) {
    v = dppReduce16(v);
    v += __int_as_float(__builtin_amdgcn_ds_swizzle(__float_as_int(v), 0x401F));
    return v;
}

// Full-wave (64) sum; result valid in lane 63.
__device__ __forceinline__ float dppReduce64(float v) {
    v = dppReduce16(v);
    v = dpp_add<0x142>(v);  // row_bcast15
    v = dpp_add<0x143>(v);  // row_bcast31
    return v;
}

// 512 threads/block, 8 waves. Grid = B = 1024 blocks; occupancy was grid-capped
// at 16 waves/CU with 256-thread blocks. min-8-waves/EU caps VGPRs at 64 so
// 4 blocks x 8 waves = 32 waves/CU can co-reside.
__global__ __launch_bounds__(512, 8) void fused_match_kernel(
    const float* __restrict__ team_embed,    // (1000,128)
    const float* __restrict__ venue_embed,   // (3,128)
    const float* __restrict__ result_embed,  // (3,128)
    const float* __restrict__ W_out,         // (517,3)
    const float* __restrict__ b_out,         // (3,)
    const float* __restrict__ goals_for,     // (B,L)
    const float* __restrict__ goals_against, // (B,L)
    const float* __restrict__ stats,         // (B,3)
    const int* __restrict__ venue,           // (B,L)
    const int* __restrict__ team,            // (B,L)
    const int* __restrict__ opponent,        // (B,L)
    const int* __restrict__ result,          // (B,L)
    const int* __restrict__ next_venue,      // (B,)
    const int* __restrict__ next_team,       // (B,)
    const int* __restrict__ next_opponent,   // (B,)
    float* __restrict__ out)                 // (B,3)
{
    const int b    = blockIdx.x;
    const int t    = threadIdx.x;
    const int lane = t & 63;
    const int wid  = t >> 6;      // 0..7
    const int half = lane >> 5;   // 0 or 1: half-wave group within wave
    const int c    = lane & 31;   // float4 column within a 128-float row
    const int gh   = t >> 5;      // global half-wave group id, 0..15

    __shared__ float  nc[384];         // next_cond: [venue | team | opponent]
    __shared__ int    s_team[L_];
    __shared__ int    s_opp[L_];
    __shared__ int    s_venue[L_];
    __shared__ float  s_e[L_];         // per-l softmax numerator exp2(kk)
    __shared__ float  s_dotv[3];
    __shared__ float4 s_accT[16][32];  // per-group team-seg accumulators
    __shared__ float4 s_accO[16][32];  // per-group opp-seg accumulators
    __shared__ float  s_redw[4][7];    // per-wave: Z, v0, v1, r0, r1, gf, ga
    __shared__ float  s_pr[517];

    const int base = b * L_;
    int   my_venue = 0, my_result = 0;
    float my_gf = 0.f, my_ga = 0.f;
    if (t < L_) {
        my_venue  = venue[base + t];
        my_result = result[base + t];
        my_gf     = goals_for[base + t];
        my_ga     = goals_against[base + t];
        s_team[t]  = team[base + t];
        s_opp[t]   = opponent[base + t];
        s_venue[t] = my_venue;
    }

    const int nv  = next_venue[b];
    const int ntm = next_team[b];
    const int nop = next_opponent[b];
    if (t < 128)      nc[t] = venue_embed[nv * H_ + t];
    else if (t < 256) nc[t] = team_embed[ntm * H_ + (t - 128)];
    else if (t < 384) nc[t] = team_embed[nop * H_ + (t - 256)];
    __syncthreads();

    // ---- the 3 venue score dots (waves 0..2), DPP wave reduce ----
    if (wid < 3) {
        float a = venue_embed[wid * H_ + lane]      * nc[lane]
                + venue_embed[wid * H_ + 64 + lane] * nc[64 + lane];
        a = dppReduce64(a);
        if (lane == 63) s_dotv[wid] = a;
    }
    __syncthreads();

    // ---- fused single-pass: score + exp2 + weighted row accumulate.
    // Half-wave group gh handles l = wid*32 + half + 2*i, i in 0..15. Each
    // lane covers one float4 column of both gathered rows; the 32-lane dot
    // reduce is 4 DPP adds + 1 ds_swizzle. Next iteration's gathers are
    // prefetched; 8 waves/SIMD provide the TLP to hide L2 latency.
    const float4 nct_c = ((const float4*)(nc + 128))[c];
    const float4 nco_c = ((const float4*)(nc + 256))[c];
    const float4* te4 = (const float4*)team_embed;
    const int lb = wid * 32 + half;   // l = lb + 2*i

    float4 accT = make_float4(0.f, 0.f, 0.f, 0.f);
    float4 accO = make_float4(0.f, 0.f, 0.f, 0.f);
    {
        float4 vT = te4[s_team[lb] * 32 + c];
        float4 vO = te4[s_opp[lb]  * 32 + c];
        float  dv = s_dotv[s_venue[lb]];

        #pragma unroll 4
        for (int i = 0; i < 16; ++i) {
            const float4 cT = vT, cO = vO;
            const float  cdv = dv;
            const int    cl  = lb + 2 * i;
            if (i < 15) {
                const int ln = cl + 2;
                vT = te4[s_team[ln] * 32 + c];
                vO = te4[s_opp[ln]  * 32 + c];
                dv = s_dotv[s_venue[ln]];
            }
            float p = cT.x * nct_c.x + cT.y * nct_c.y + cT.z * nct_c.z + cT.w * nct_c.w
                    + cO.x * nco_c.x + cO.y * nco_c.y + cO.z * nco_c.z + cO.w * nco_c.w;
            p = reduce32(p);                             // sum in all 32 lanes
            const float e = exp2f((p + cdv) * KSCALE);   // softmax numerator
            if (c == 0) s_e[cl] = e;
            accT.x += e * cT.x; accT.y += e * cT.y; accT.z += e * cT.z; accT.w += e * cT.w;
            accO.x += e * cO.x; accO.y += e * cO.y; accO.z += e * cO.z; accO.w += e * cO.w;
        }
    }
    s_accT[gh][c] = accT;
    s_accO[gh][c] = accO;
    __syncthreads();

    // ---- bucket pass (waves 0..3): Z + {v0,v1, r0,r1, gf, ga} sums ----
    // (venue2/result2 recovered by complement)
    if (t < L_) {
        const float e = s_e[t];
        float vals[7];
        vals[0] = e;
        vals[1] = (my_venue  == 0) ? e : 0.f;
        vals[2] = (my_venue  == 1) ? e : 0.f;
        vals[3] = (my_result == 0) ? e : 0.f;
        vals[4] = (my_result == 1) ? e : 0.f;
        vals[5] = e * my_gf;
        vals[6] = e * my_ga;
        #pragma unroll
        for (int k = 0; k < 7; ++k) vals[k] = dppReduce64(vals[k]);
        if (lane == 63) {
            #pragma unroll
            for (int k = 0; k < 7; ++k) s_redw[wid][k] = vals[k];
        }
    }
    __syncthreads();

    #define RW(k) (s_redw[0][k] + s_redw[1][k] + s_redw[2][k] + s_redw[3][k])

    // ---- assemble past_repr (517) across all 512 threads ----
    if (t < 64) {
        const int seg = t >> 5;   // 0: team dims 128.., 1: opp dims 256..
        const int cc  = t & 31;
        const float4 (*acc)[32] = seg ? s_accO : s_accT;
        float4 a = make_float4(0.f, 0.f, 0.f, 0.f);
        #pragma unroll
        for (int h = 0; h < 16; ++h) {
            const float4 v = acc[h][cc];
            a.x += v.x; a.y += v.y; a.z += v.z; a.w += v.w;
        }
        const float invZ = 1.f / RW(0);
        const int d = 128 + seg * 128 + cc * 4;
        s_pr[d + 0] = a.x * invZ;
        s_pr[d + 1] = a.y * invZ;
        s_pr[d + 2] = a.z * invZ;
        s_pr[d + 3] = a.w * invZ;
    } else if (t < 192) {
        const int j = t - 64;  // venue dims 0..127
        const float invZ = 1.f / RW(0);
        const float w0 = RW(1) * invZ;
        const float w1 = RW(2) * invZ;
        const float w2 = 1.f - w0 - w1;
        s_pr[j] = w0 * venue_embed[j] + w1 * venue_embed[H_ + j]
                + w2 * venue_embed[2 * H_ + j];
    } else if (t < 320) {
        const int j = t - 192;  // result dims 384..511, one per thread
        const float invZ = 1.f / RW(0);
        const float w3 = RW(3) * invZ;
        const float w4 = RW(4) * invZ;
        const float w5 = 1.f - w3 - w4;
        s_pr[384 + j] = w3 * result_embed[j] + w4 * result_embed[H_ + j]
                      + w5 * result_embed[2 * H_ + j];
    } else if (t < 322) {
        s_pr[512 + (t - 320)] = RW(5 + (t - 320)) / RW(0);         // goal sums
    } else if (t < 325) {
        s_pr[514 + (t - 322)] = stats[b * 3 + (t - 322)];          // stats
    }
    #undef RW
    __syncthreads();

    // ---- logits: wave r computes output r (517-length dot) ----
    if (wid < 3) {
        float acc = 0.f;
        for (int d = lane; d < 517; d += 64) acc += s_pr[d] * W_out[d * 3 + wid];
        acc = dppReduce64(acc);
        if (lane == 63) out[b * 3 + wid] = acc + b_out[wid];
    }
}

extern "C" void kernel_launch(void* const* d_in, const int* in_sizes, int n_in,
                              void* d_out, int out_size, void* d_ws, size_t ws_size,
                              hipStream_t stream) {
    const float* team_embed    = (const float*)d_in[0];
    const float* venue_embed   = (const float*)d_in[1];
    const float* result_embed  = (const float*)d_in[2];
    const float* W_out         = (const float*)d_in[3];
    const float* b_out         = (const float*)d_in[4];
    const float* goals_for     = (const float*)d_in[5];
    const float* goals_against = (const float*)d_in[6];
    const float* stats         = (const float*)d_in[7];
    const int* venue           = (const int*)d_in[8];
    const int* team            = (const int*)d_in[9];
    const int* opponent        = (const int*)d_in[10];
    const int* result          = (const int*)d_in[11];
    const int* next_venue      = (const int*)d_in[12];
    const int* next_team       = (const int*)d_in[13];
    const int* next_opponent   = (const int*)d_in[14];
    float* out = (float*)d_out;

    const int B = in_sizes[12];  // next_venue has B elements
    fused_match_kernel<<<B, 512, 0, stream>>>(
        team_embed, venue_embed, result_embed, W_out, b_out,
        goals_for, goals_against, stats,
        venue, team, opponent, result,
        next_venue, next_team, next_opponent, out);
}

// Round 4
// 101.163 us; speedup vs baseline: 1.0487x; 1.0487x over previous
//
#include <hip/hip_runtime.h>

// Problem constants (match reference): B=1024, L=256, H=128
#define L_ 256
#define H_ 128

// base-2 softmax scale: (1/sqrt(384)) * log2(e)
// Scores are tiny (embeddings ~N(0,0.02^2) => |kk| < ~0.1): exp2 without
// max-subtraction is safe; softmax is shift-invariant. (Verified rounds 2-3:
// absmax unchanged at 6.1e-5.)
#define KSCALE 0.07362222315f

// ---- DPP cross-lane adds (VALU-latency; no LDS in the critical path) ----
template <int CTRL>
__device__ __forceinline__ float dpp_add(float v) {
    return v + __int_as_float(__builtin_amdgcn_update_dpp(
        0, __float_as_int(v), CTRL, 0xF, 0xF, true));
}

// Sum across each 16-lane row; result valid in ALL 16 lanes.
__device__ __forceinline__ float dppReduce16(float v) {
    v = dpp_add<0xB1>(v);   // quad_perm [1,0,3,2]
    v = dpp_add<0x4E>(v);   // quad_perm [2,3,0,1]
    v = dpp_add<0x141>(v);  // row_half_mirror
    v = dpp_add<0x140>(v);  // row_mirror
    return v;
}

// Full-wave (64) sum; result valid in lane 63.
__device__ __forceinline__ float dppReduce64(float v) {
    v = dppReduce16(v);
    v = dpp_add<0x142>(v);  // row_bcast15
    v = dpp_add<0x143>(v);  // row_bcast31
    return v;
}

__global__ __launch_bounds__(256) void fused_match_kernel(
    const float* __restrict__ team_embed,    // (1000,128)
    const float* __restrict__ venue_embed,   // (3,128)
    const float* __restrict__ result_embed,  // (3,128)
    const float* __restrict__ W_out,         // (517,3)
    const float* __restrict__ b_out,         // (3,)
    const float* __restrict__ goals_for,     // (B,L)
    const float* __restrict__ goals_against, // (B,L)
    const float* __restrict__ stats,         // (B,3)
    const int* __restrict__ venue,           // (B,L)
    const int* __restrict__ team,            // (B,L)
    const int* __restrict__ opponent,        // (B,L)
    const int* __restrict__ result,          // (B,L)
    const int* __restrict__ next_venue,      // (B,)
    const int* __restrict__ next_team,       // (B,)
    const int* __restrict__ next_opponent,   // (B,)
    float* __restrict__ out)                 // (B,3)
{
    const int b    = blockIdx.x;
    const int t    = threadIdx.x;
    const int lane = t & 63;
    const int wid  = t >> 6;
    const int grp  = lane >> 4;   // 4 groups of 16 lanes per wave; one l per group
    const int ci   = lane & 15;   // float4 column (low half) within a 128-float row

    __shared__ float  nc[384];         // next_cond: [venue | team | opponent]
    __shared__ int    s_team[L_];
    __shared__ int    s_opp[L_];
    __shared__ float  s_e[L_];         // per-l softmax numerator exp2(kk)
    __shared__ float  s_dv[L_];        // venue-dot addend per l (raw units)
    __shared__ float  s_dotv[3];
    __shared__ float4 s_accT[16][32];  // per-group team-seg accumulators
    __shared__ float4 s_accO[16][32];  // per-group opp-seg accumulators
    __shared__ float  s_redw[4][7];    // per-wave: Z, v0, v1, r0, r1, gf, ga
    __shared__ float  s_pr[517];

    const int base = b * L_;
    const int my_venue  = venue[base + t];
    const int my_result = result[base + t];
    const float my_gf   = goals_for[base + t];
    const float my_ga   = goals_against[base + t];
    s_team[t] = team[base + t];
    s_opp[t]  = opponent[base + t];

    const int nv  = next_venue[b];
    const int ntm = next_team[b];
    const int nop = next_opponent[b];
    if (t < 128) {
        nc[t]       = venue_embed[nv * H_ + t];
        nc[128 + t] = team_embed[ntm * H_ + t];
    } else {
        nc[128 + t] = team_embed[nop * H_ + (t - 128)];  // 256..383
    }
    __syncthreads();

    // ---- the 3 venue score dots (waves 0..2), DPP wave reduce ----
    if (wid < 3) {
        float a = venue_embed[wid * H_ + lane]      * nc[lane]
                + venue_embed[wid * H_ + 64 + lane] * nc[64 + lane];
        a = dppReduce64(a);
        if (lane == 63) s_dotv[wid] = a;
    }
    __syncthreads();
    s_dv[t] = s_dotv[my_venue];
    __syncthreads();

    // ---- fused single-pass: score + exp2 + weighted row accumulate.
    // 16-lane group grp of wave wid handles l = wid*64 + i*4 + grp. Each lane
    // covers float4 columns ci and ci+16 of both gathered rows; the 16-lane
    // dot reduce is 4 DPP adds (VALU). No manual prefetch (regressed in R2 —
    // compiler schedules the gathers better itself); no online max (scores
    // bounded tiny, softmax shift-invariant).
    const float4 nct0 = ((const float4*)(nc + 128))[ci];
    const float4 nct1 = ((const float4*)(nc + 128))[ci + 16];
    const float4 nco0 = ((const float4*)(nc + 256))[ci];
    const float4 nco1 = ((const float4*)(nc + 256))[ci + 16];

    const int lb = wid * 64;
    float4 accT0 = make_float4(0.f, 0.f, 0.f, 0.f);
    float4 accT1 = make_float4(0.f, 0.f, 0.f, 0.f);
    float4 accO0 = make_float4(0.f, 0.f, 0.f, 0.f);
    float4 accO1 = make_float4(0.f, 0.f, 0.f, 0.f);
    #pragma unroll 2
    for (int i = 0; i < 16; ++i) {
        const int l = lb + i * 4 + grp;
        const float4* rT = (const float4*)team_embed + s_team[l] * 32;
        const float4* rO = (const float4*)team_embed + s_opp[l]  * 32;
        const float4 vT0 = rT[ci];
        const float4 vT1 = rT[ci + 16];
        const float4 vO0 = rO[ci];
        const float4 vO1 = rO[ci + 16];
        float p = vT0.x * nct0.x + vT0.y * nct0.y + vT0.z * nct0.z + vT0.w * nct0.w
                + vT1.x * nct1.x + vT1.y * nct1.y + vT1.z * nct1.z + vT1.w * nct1.w
                + vO0.x * nco0.x + vO0.y * nco0.y + vO0.z * nco0.z + vO0.w * nco0.w
                + vO1.x * nco1.x + vO1.y * nco1.y + vO1.z * nco1.z + vO1.w * nco1.w;
        p = dppReduce16(p);                            // sum in all 16 lanes
        const float e = exp2f((p + s_dv[l]) * KSCALE); // softmax numerator
        if (ci == 0) s_e[l] = e;
        accT0.x += e * vT0.x; accT0.y += e * vT0.y; accT0.z += e * vT0.z; accT0.w += e * vT0.w;
        accT1.x += e * vT1.x; accT1.y += e * vT1.y; accT1.z += e * vT1.z; accT1.w += e * vT1.w;
        accO0.x += e * vO0.x; accO0.y += e * vO0.y; accO0.z += e * vO0.z; accO0.w += e * vO0.w;
        accO1.x += e * vO1.x; accO1.y += e * vO1.y; accO1.z += e * vO1.z; accO1.w += e * vO1.w;
    }
    {
        const int hs = wid * 4 + grp;
        s_accT[hs][ci]      = accT0;
        s_accT[hs][ci + 16] = accT1;
        s_accO[hs][ci]      = accO0;
        s_accO[hs][ci + 16] = accO1;
    }
    __syncthreads();

    // ---- bucket pass: Z + {v0,v1, r0,r1, gf, ga} sums ----
    // (venue2/result2 recovered by complement: w2 = 1 - w0 - w1)
    {
        const float e = s_e[t];
        float vals[7];
        vals[0] = e;
        vals[1] = (my_venue  == 0) ? e : 0.f;
        vals[2] = (my_venue  == 1) ? e : 0.f;
        vals[3] = (my_result == 0) ? e : 0.f;
        vals[4] = (my_result == 1) ? e : 0.f;
        vals[5] = e * my_gf;
        vals[6] = e * my_ga;
        #pragma unroll
        for (int k = 0; k < 7; ++k) vals[k] = dppReduce64(vals[k]);
        if (lane == 63) {
            #pragma unroll
            for (int k = 0; k < 7; ++k) s_redw[wid][k] = vals[k];
        }
    }
    __syncthreads();

    #define RW(k) (s_redw[0][k] + s_redw[1][k] + s_redw[2][k] + s_redw[3][k])

    // ---- assemble past_repr (517) ----
    if (t < 64) {
        const int seg = t >> 5;   // 0: team dims 128.., 1: opp dims 256..
        const int cc  = t & 31;
        float4 a = make_float4(0.f, 0.f, 0.f, 0.f);
        #pragma unroll
        for (int h = 0; h < 16; ++h) {
            const float4 v = seg ? s_accO[h][cc] : s_accT[h][cc];
            a.x += v.x; a.y += v.y; a.z += v.z; a.w += v.w;
        }
        const float invZ = 1.f / RW(0);
        const int d = 128 + seg * 128 + cc * 4;
        s_pr[d + 0] = a.x * invZ;
        s_pr[d + 1] = a.y * invZ;
        s_pr[d + 2] = a.z * invZ;
        s_pr[d + 3] = a.w * invZ;
        if (t < 2) s_pr[512 + t] = RW(5 + t) * invZ;               // goal sums
        if (t >= 2 && t < 5) s_pr[512 + t] = stats[b * 3 + t - 2]; // stats 514..516
    } else if (t < 192) {
        const int j = t - 64;  // venue dims 0..127, bucketed 3-term combo
        const float invZ = 1.f / RW(0);
        const float w0 = RW(1) * invZ;
        const float w1 = RW(2) * invZ;
        const float w2 = 1.f - w0 - w1;
        s_pr[j] = w0 * venue_embed[j] + w1 * venue_embed[H_ + j]
                + w2 * venue_embed[2 * H_ + j];
    } else {
        const int j = t - 192;  // result dims 384..511, two per thread
        const float invZ = 1.f / RW(0);
        const float w3 = RW(3) * invZ;
        const float w4 = RW(4) * invZ;
        const float w5 = 1.f - w3 - w4;
        s_pr[384 + j] = w3 * result_embed[j]      + w4 * result_embed[H_ + j]
                      + w5 * result_embed[2 * H_ + j];
        s_pr[448 + j] = w3 * result_embed[64 + j] + w4 * result_embed[H_ + 64 + j]
                      + w5 * result_embed[2 * H_ + 64 + j];
    }
    #undef RW
    __syncthreads();

    // ---- logits: wave r computes output r (517-length dot) ----
    if (wid < 3) {
        float acc = 0.f;
        for (int d = lane; d < 517; d += 64) acc += s_pr[d] * W_out[d * 3 + wid];
        acc = dppReduce64(acc);
        if (lane == 63) out[b * 3 + wid] = acc + b_out[wid];
    }
}

extern "C" void kernel_launch(void* const* d_in, const int* in_sizes, int n_in,
                              void* d_out, int out_size, void* d_ws, size_t ws_size,
                              hipStream_t stream) {
    const float* team_embed    = (const float*)d_in[0];
    const float* venue_embed   = (const float*)d_in[1];
    const float* result_embed  = (const float*)d_in[2];
    const float* W_out         = (const float*)d_in[3];
    const float* b_out         = (const float*)d_in[4];
    const float* goals_for     = (const float*)d_in[5];
    const float* goals_against = (const float*)d_in[6];
    const float* stats         = (const float*)d_in[7];
    const int* venue           = (const int*)d_in[8];
    const int* team            = (const int*)d_in[9];
    const int* opponent        = (const int*)d_in[10];
    const int* result          = (const int*)d_in[11];
    const int* next_venue      = (const int*)d_in[12];
    const int* next_team       = (const int*)d_in[13];
    const int* next_opponent   = (const int*)d_in[14];
    float* out = (float*)d_out;

    const int B = in_sizes[12];  // next_venue has B elements
    fused_match_kernel<<<B, 256, 0, stream>>>(
        team_embed, venue_embed, result_embed, W_out, b_out,
        goals_for, goals_against, stats,
        venue, team, opponent, result,
        next_venue, next_team, next_opponent, out);
}